// Round 2
// baseline (970.221 us; speedup 1.0000x reference)
//
#include <hip/hip_runtime.h>

typedef float f4 __attribute__((ext_vector_type(4)));
typedef int i4 __attribute__((ext_vector_type(4)));
typedef __bf16 bf16x8 __attribute__((ext_vector_type(8)));
typedef unsigned short u16;

#define DEV static __device__ __forceinline__

// gfx950 builtin MFMA (hazard-safe, schedulable; inline asm lacked wait-states)
DEV f4 mfma_bf16(bf16x8 a, bf16x8 b, f4 c) {
  return __builtin_amdgcn_mfma_f32_16x16x32_bf16(a, b, c, 0, 0, 0);
}

DEV bf16x8 ld_frag(const u16* p) {  // 16B LDS load -> bf16x8 fragment
  union { i4 i; bf16x8 b; } u;
  u.i = *(const i4*)p;
  return u.b;
}

DEV u16 f2bf(float f) {  // RNE f32 -> bf16 bits
  union { float f; unsigned int u; } v; v.f = f;
  return (u16)((v.u + 0x7fffu + ((v.u >> 16) & 1u)) >> 16);
}

// async global->LDS, 16B/lane; LDS dest is wave-uniform base + lane*16
DEV void async_cp16(const void* g, void* l) {
  __builtin_amdgcn_global_load_lds((const __attribute__((address_space(1))) void*)g,
                                   (__attribute__((address_space(3))) void*)l, 16, 0, 0);
}

// ---------- x: (B,C,THW) f32 -> xt: (B*THW, C) bf16 ----------
__global__ __launch_bounds__(256) void k_transpose_x(const float* __restrict__ x,
                                                     u16* __restrict__ xt) {
  __shared__ float tile[32][33];
  const int b = blockIdx.z;
  const int thw0 = blockIdx.x * 32;
  const int c0 = blockIdx.y * 32;
  const int tc = threadIdx.x & 31;
  const int tr = threadIdx.x >> 5;  // 0..7
#pragma unroll
  for (int i = 0; i < 4; i++) {
    int c = tr + i * 8;
    tile[c][tc] = x[(long)(b * 512 + c0 + c) * 16384 + thw0 + tc];
  }
  __syncthreads();
#pragma unroll
  for (int i = 0; i < 4; i++) {
    int r = tr + i * 8;
    xt[(long)(b * 16384 + thw0 + r) * 512 + c0 + tc] = f2bf(tile[tc][r]);
  }
}

// ---------- pack weights: Wqkv (4608,512) bf16, WoCat (512,1536) bf16, bo sum ----------
__global__ __launch_bounds__(256) void k_prep_w(
    const float* wq_w, const float* wk_w, const float* wv_w, const float* wo_w, const float* bo_w,
    const float* wq_h, const float* wk_h, const float* wv_h, const float* wo_h, const float* bo_h,
    const float* wq_t, const float* wk_t, const float* wv_t, const float* wo_t, const float* bo_t,
    u16* Wqkv, u16* WoCat, float* bo) {
  const int idx = blockIdx.x * 256 + threadIdx.x;
  if (idx < 2359296) {  // Wqkv row j = a*1536 + which*512 + co, col ci
    int j = idx >> 9, ci = idx & 511;
    int sel = j >> 9, co = j & 511;  // sel = a*3+which
    const float* s;
    switch (sel) {
      case 0: s = wq_w; break; case 1: s = wk_w; break; case 2: s = wv_w; break;
      case 3: s = wq_h; break; case 4: s = wk_h; break; case 5: s = wv_h; break;
      case 6: s = wq_t; break; case 7: s = wk_t; break; default: s = wv_t; break;
    }
    Wqkv[idx] = f2bf(s[co * 512 + ci]);
  } else if (idx < 2359296 + 786432) {  // WoCat[c][a*512+ci] = Wo_a[c][ci]
    int t = idx - 2359296;
    int c = t / 1536, j2 = t - c * 1536;
    int a = j2 >> 9, ci = j2 & 511;
    const float* s = (a == 0) ? wo_w : (a == 1) ? wo_h : wo_t;
    WoCat[t] = f2bf(s[c * 512 + ci]);
  } else if (idx < 2359296 + 786432 + 512) {
    int c = idx - (2359296 + 786432);
    bo[c] = bo_w[c] + bo_h[c] + bo_t[c];
  }
}

// ---------- GEMM: C(MxN) = A(MxK) * Bt(NxK)^T, bf16 in, 128x128 tile, BK=64 ----------
// EPI 0: bf16 row-major out (ldc), LDS-repacked coalesced 16B stores
// EPI 1: fp32 out scattered to (B,C,THW) layout (+bias); rows=c, cols=token n
template <int EPI>
__global__ __launch_bounds__(256, 2) void k_gemm_bt(
    const u16* __restrict__ A, const u16* __restrict__ Bt, void* __restrict__ Cp,
    const float* __restrict__ bias, int K, int lda, int ldb, int ldc) {
  __shared__ __attribute__((aligned(16))) u16 lds[20480];  // 32KiB stage / 40KiB epilogue
  u16* ldsA = lds;
  u16* ldsB = lds + 8192;
  const int tid = threadIdx.x;
  const int lane = tid & 63, wave = tid >> 6;
  const int cl = lane & 15, q = lane >> 4;
  const int wm = (wave >> 1) * 64, wn = (wave & 1) * 64;
  const long m0 = (long)blockIdx.y * 128;
  const long n0 = (long)blockIdx.x * 128;
  const u16* Ab = A + m0 * lda;
  const u16* Bb = Bt + n0 * ldb;

  // staging: slot s holds global chunk (s&7)^(row&7) of row s>>3  (XOR swizzle)
  long a_off[4], b_off[4];
  u16 *a_dst[4], *b_dst[4];
#pragma unroll
  for (int i = 0; i < 4; i++) {
    int s = i * 256 + tid;
    int row = s >> 3;
    int gc = (s & 7) ^ (row & 7);
    a_off[i] = (long)row * lda + gc * 8;
    b_off[i] = (long)row * ldb + gc * 8;
    int slot0 = i * 256 + (tid & 192);  // wave-uniform LDS base
    a_dst[i] = ldsA + slot0 * 8;
    b_dst[i] = ldsB + slot0 * 8;
  }

  f4 acc[4][4];
  {
    f4 z; z[0] = z[1] = z[2] = z[3] = 0.f;
#pragma unroll
    for (int i = 0; i < 4; i++)
#pragma unroll
      for (int j = 0; j < 4; j++) acc[i][j] = z;
  }

  for (int kt = 0; kt < K; kt += 64) {
#pragma unroll
    for (int i = 0; i < 4; i++) {
      async_cp16(Ab + a_off[i] + kt, a_dst[i]);
      async_cp16(Bb + b_off[i] + kt, b_dst[i]);
    }
    __syncthreads();
#pragma unroll
    for (int kk = 0; kk < 2; kk++) {
      bf16x8 afr[4], bfr[4];
#pragma unroll
      for (int im = 0; im < 4; im++) {
        int row = wm + im * 16 + cl;
        int ch = (kk * 4 + q) ^ (row & 7);
        afr[im] = ld_frag(ldsA + row * 64 + ch * 8);
      }
#pragma unroll
      for (int in = 0; in < 4; in++) {
        int row = wn + in * 16 + cl;
        int ch = (kk * 4 + q) ^ (row & 7);
        bfr[in] = ld_frag(ldsB + row * 64 + ch * 8);
      }
#pragma unroll
      for (int im = 0; im < 4; im++)
#pragma unroll
        for (int in = 0; in < 4; in++)
          acc[im][in] = mfma_bf16(afr[im], bfr[in], acc[im][in]);
    }
    __syncthreads();
  }

  if (EPI == 0) {
    u16* myl = lds + wave * 5120;  // 64 rows x 80 (16B-aligned rows)
#pragma unroll
    for (int im = 0; im < 4; im++)
#pragma unroll
      for (int in = 0; in < 4; in++)
#pragma unroll
        for (int r = 0; r < 4; r++)
          myl[(im * 16 + q * 4 + r) * 80 + in * 16 + cl] = f2bf(acc[im][in][r]);
    __syncthreads();
    u16* Co = (u16*)Cp;
#pragma unroll
    for (int it = 0; it < 8; it++) {
      int lr = it * 8 + (lane >> 3);
      int lc = (lane & 7) * 8;
      i4 v = *(const i4*)(myl + lr * 80 + lc);
      *(i4*)(Co + (m0 + wm + lr) * ldc + n0 + wn + lc) = v;
    }
  } else {
    float* Co = (float*)Cp;
#pragma unroll
    for (int im = 0; im < 4; im++)
#pragma unroll
      for (int r = 0; r < 4; r++) {
        int c = (int)m0 + wm + im * 16 + q * 4 + r;
        float bv = bias[c];
#pragma unroll
        for (int in = 0; in < 4; in++) {
          long n = n0 + wn + in * 16 + cl;  // token; 16 lanes -> consecutive thw
          long b = n >> 14, thw = n & 16383;
          Co[((b * 512 + c) << 14) + thw] = acc[im][in][r] + bv;
        }
      }
  }
}

// ---------- axial attention: 1 wave per (group, head), MFMA QK^T and PV ----------
template <int L>
__global__ __launch_bounds__(64) void k_attn(
    const u16* __restrict__ QKV, u16* __restrict__ Oc,
    int inner, int istride, int ostride, int obase, int tstride) {
  constexpr int NT = L / 16;
  __shared__ __attribute__((aligned(16))) u16 sQ[2048];   // 32x64
  __shared__ __attribute__((aligned(16))) u16 sK[2048];   // 32x64
  __shared__ __attribute__((aligned(16))) u16 sVt[2560];  // 64ch x 40 (32 tok + pad)
  __shared__ __attribute__((aligned(16))) u16 sP[1280];   // 32 x 40
  const int lane = threadIdx.x;
  const int cl = lane & 15, q = lane >> 4;
  const int g = blockIdx.x, head = blockIdx.y;
  const long tok0 = (long)(g / inner) * ostride + (long)(g % inner) * istride;
  const long rs = (long)tstride * 1536;
  const u16* qb = QKV + tok0 * 1536 + head * 64;
  const u16* kb = qb + 512;
  const u16* vb = qb + 1024;

  if (L == 16) {  // zero K-dim padding (cols 16..31 of P and Vt must be 0)
    unsigned int* z1 = (unsigned int*)sVt;
    for (int i = lane; i < 1280; i += 64) z1[i] = 0;
    unsigned int* z2 = (unsigned int*)sP;
    for (int i = lane; i < 640; i += 64) z2[i] = 0;
  }

#pragma unroll
  for (int i = 0; i < L / 8; i++) {  // Q,K swizzled async stage
    int s = i * 64 + lane;
    int row = s >> 3;
    int gc = (s & 7) ^ (row & 7);
    async_cp16(qb + row * rs + gc * 8, (char*)sQ + i * 1024);
    async_cp16(kb + row * rs + gc * 8, (char*)sK + i * 1024);
  }
#pragma unroll
  for (int i = 0; i < L / 8; i++) {  // V load + transpose into sVt[ch][tok]
    int s = i * 64 + lane;
    int row = s >> 3, c8 = s & 7;
    union { i4 v; u16 h[8]; } raw;
    raw.v = *(const i4*)(vb + row * rs + c8 * 8);
#pragma unroll
    for (int j = 0; j < 8; j++) sVt[(c8 * 8 + j) * 40 + row] = raw.h[j];
  }
  __syncthreads();

  // S = Q K^T
  f4 sacc[NT][NT];
  { f4 z; z[0]=z[1]=z[2]=z[3]=0.f;
    for (int a = 0; a < NT; a++) for (int b2 = 0; b2 < NT; b2++) sacc[a][b2] = z; }
#pragma unroll
  for (int kk = 0; kk < 2; kk++) {
    bf16x8 qf[NT], kf[NT];
#pragma unroll
    for (int t = 0; t < NT; t++) {
      int row = t * 16 + cl;
      int ch = (kk * 4 + q) ^ (row & 7);
      qf[t] = ld_frag(sQ + row * 64 + ch * 8);
      kf[t] = ld_frag(sK + row * 64 + ch * 8);
    }
#pragma unroll
    for (int rt = 0; rt < NT; rt++)
#pragma unroll
      for (int ct = 0; ct < NT; ct++)
        sacc[rt][ct] = mfma_bf16(qf[rt], kf[ct], sacc[rt][ct]);
  }

  // softmax over keys; C-layout: row = q*4+i (+16*rt), col = cl (+16*ct)
#pragma unroll
  for (int rt = 0; rt < NT; rt++)
#pragma unroll
    for (int ct = 0; ct < NT; ct++)
#pragma unroll
      for (int i = 0; i < 4; i++) sacc[rt][ct][i] *= 0.125f;  // 1/sqrt(64)
#pragma unroll
  for (int rt = 0; rt < NT; rt++)
#pragma unroll
    for (int i = 0; i < 4; i++) {
      float m = sacc[rt][0][i];
#pragma unroll
      for (int ct = 1; ct < NT; ct++) m = fmaxf(m, sacc[rt][ct][i]);
      for (int off = 1; off < 16; off <<= 1) m = fmaxf(m, __shfl_xor(m, off, 64));
      float ssum = 0.f;
#pragma unroll
      for (int ct = 0; ct < NT; ct++) {
        float p = __expf(sacc[rt][ct][i] - m);
        sacc[rt][ct][i] = p;
        ssum += p;
      }
      for (int off = 1; off < 16; off <<= 1) ssum += __shfl_xor(ssum, off, 64);
      float inv = 1.0f / ssum;
#pragma unroll
      for (int ct = 0; ct < NT; ct++) sacc[rt][ct][i] *= inv;
    }

  // P -> LDS (A-operand layout source)
#pragma unroll
  for (int rt = 0; rt < NT; rt++)
#pragma unroll
    for (int ct = 0; ct < NT; ct++)
#pragma unroll
      for (int i = 0; i < 4; i++)
        sP[(rt * 16 + q * 4 + i) * 40 + ct * 16 + cl] = f2bf(sacc[rt][ct][i]);
  __syncthreads();

  // O = P V  (K=32, padded with zeros when L=16)
  bf16x8 pf[NT], vf[4];
#pragma unroll
  for (int mt = 0; mt < NT; mt++) pf[mt] = ld_frag(sP + (mt * 16 + cl) * 40 + q * 8);
#pragma unroll
  for (int nt = 0; nt < 4; nt++) vf[nt] = ld_frag(sVt + (nt * 16 + cl) * 40 + q * 8);
  f4 oacc[NT][4];
  { f4 z; z[0]=z[1]=z[2]=z[3]=0.f;
    for (int a = 0; a < NT; a++) for (int b2 = 0; b2 < 4; b2++) oacc[a][b2] = z; }
#pragma unroll
  for (int mt = 0; mt < NT; mt++)
#pragma unroll
    for (int nt = 0; nt < 4; nt++)
      oacc[mt][nt] = mfma_bf16(pf[mt], vf[nt], oacc[mt][nt]);

#pragma unroll
  for (int mt = 0; mt < NT; mt++)
#pragma unroll
    for (int i = 0; i < 4; i++) {
      int r = mt * 16 + q * 4 + i;  // token within group
      u16* dst = Oc + (tok0 + (long)r * tstride) * 1536 + obase + head * 64;
#pragma unroll
      for (int nt = 0; nt < 4; nt++) dst[nt * 16 + cl] = f2bf(oacc[mt][nt][i]);
    }
}

extern "C" void kernel_launch(void* const* d_in, const int* in_sizes, int n_in,
                              void* d_out, int out_size, void* d_ws, size_t ws_size,
                              hipStream_t stream) {
  (void)in_sizes; (void)n_in; (void)out_size; (void)ws_size;
  const float* x    = (const float*)d_in[0];
  const float* wq_w = (const float*)d_in[1];
  const float* wk_w = (const float*)d_in[2];
  const float* wv_w = (const float*)d_in[3];
  const float* wo_w = (const float*)d_in[4];
  const float* bo_w = (const float*)d_in[5];
  const float* wq_h = (const float*)d_in[6];
  const float* wk_h = (const float*)d_in[7];
  const float* wv_h = (const float*)d_in[8];
  const float* wo_h = (const float*)d_in[9];
  const float* bo_h = (const float*)d_in[10];
  const float* wq_t = (const float*)d_in[11];
  const float* wk_t = (const float*)d_in[12];
  const float* wv_t = (const float*)d_in[13];
  const float* wo_t = (const float*)d_in[14];
  const float* bo_t = (const float*)d_in[15];

  char* ws = (char*)d_ws;
  u16* xt    = (u16*)(ws);                 //  64 MiB  (65536 x 512 bf16)
  u16* qkv   = (u16*)(ws + 67108864L);     // 192 MiB  (65536 x 1536 bf16, per-branch)
  u16* oc    = (u16*)(ws + 268435456L);    // 192 MiB  (65536 x 1536 bf16 concat)
  u16* Wqkv  = (u16*)(ws + 469762048L);    // 4.5 MiB
  u16* WoCat = (u16*)(ws + 474480640L);    // 1.5 MiB
  float* bo  = (float*)(ws + 476053504L);  // 2 KiB

  k_transpose_x<<<dim3(512, 16, 4), 256, 0, stream>>>(x, xt);
  k_prep_w<<<dim3(12290), 256, 0, stream>>>(wq_w, wk_w, wv_w, wo_w, bo_w,
                                            wq_h, wk_h, wv_h, wo_h, bo_h,
                                            wq_t, wk_t, wv_t, wo_t, bo_t,
                                            Wqkv, WoCat, bo);
  for (int a = 0; a < 3; a++) {
    // QKV projection for branch a: (65536x512) @ (1536x512)^T -> (65536x1536) bf16
    k_gemm_bt<0><<<dim3(12, 512), 256, 0, stream>>>(
        xt, Wqkv + (long)a * 1536 * 512, (void*)qkv, nullptr, 512, 512, 512, 1536);
    if (a == 0)        // width:  tok0 = g*32, stride 1
      k_attn<32><<<dim3(2048, 8), 64, 0, stream>>>(qkv, oc, 1, 0, 32, 0, 1);
    else if (a == 1)   // height: tok0 = (g/32)*1024 + g%32, stride 32
      k_attn<32><<<dim3(2048, 8), 64, 0, stream>>>(qkv, oc, 32, 1, 1024, 512, 32);
    else               // time:   tok0 = (g/1024)*16384 + g%1024, stride 1024, L=16
      k_attn<16><<<dim3(4096, 8), 64, 0, stream>>>(qkv, oc, 1024, 1, 16384, 1024, 1024);
  }
  // Out^T = WoCat(512x1536) @ oc(65536x1536)^T, +bias, scattered to (B,C,T,H,W) f32
  k_gemm_bt<1><<<dim3(512, 4), 256, 0, stream>>>(
      WoCat, oc, d_out, bo, 1536, 1536, 1536, 0);
}

// Round 3
// 969.805 us; speedup vs baseline: 1.0004x; 1.0004x over previous
//
#include <hip/hip_runtime.h>

typedef float f4 __attribute__((ext_vector_type(4)));
typedef int i4 __attribute__((ext_vector_type(4)));
typedef __bf16 bf16x8 __attribute__((ext_vector_type(8)));
typedef unsigned short u16;

#define DEV static __device__ __forceinline__

// gfx950 builtin MFMA (hazard-safe, schedulable; inline asm lacked wait-states)
DEV f4 mfma_bf16(bf16x8 a, bf16x8 b, f4 c) {
  return __builtin_amdgcn_mfma_f32_16x16x32_bf16(a, b, c, 0, 0, 0);
}

DEV bf16x8 ld_frag(const u16* p) {  // 16B LDS load -> bf16x8 fragment
  union { i4 i; bf16x8 b; } u;
  u.i = *(const i4*)p;
  return u.b;
}

DEV u16 f2bf(float f) {  // RNE f32 -> bf16 bits
  union { float f; unsigned int u; } v; v.f = f;
  return (u16)((v.u + 0x7fffu + ((v.u >> 16) & 1u)) >> 16);
}

// async global->LDS, 16B/lane; LDS dest is wave-uniform base + lane*16
DEV void async_cp16(const void* g, void* l) {
  __builtin_amdgcn_global_load_lds((const __attribute__((address_space(1))) void*)g,
                                   (__attribute__((address_space(3))) void*)l, 16, 0, 0);
}

// ---------- x: (B,C,THW) f32 -> xt: (B*THW, C) bf16 ----------
__global__ __launch_bounds__(256) void k_transpose_x(const float* __restrict__ x,
                                                     u16* __restrict__ xt) {
  __shared__ float tile[32][33];
  const int b = blockIdx.z;
  const int thw0 = blockIdx.x * 32;
  const int c0 = blockIdx.y * 32;
  const int tc = threadIdx.x & 31;
  const int tr = threadIdx.x >> 5;  // 0..7
#pragma unroll
  for (int i = 0; i < 4; i++) {
    int c = tr + i * 8;
    tile[c][tc] = x[(long)(b * 512 + c0 + c) * 16384 + thw0 + tc];
  }
  __syncthreads();
#pragma unroll
  for (int i = 0; i < 4; i++) {
    int r = tr + i * 8;
    xt[(long)(b * 16384 + thw0 + r) * 512 + c0 + tc] = f2bf(tile[tc][r]);
  }
}

// ---------- pack weights: Wqkv (4608,512) bf16, WoCat (512,1536) bf16, bo sum ----------
__global__ __launch_bounds__(256) void k_prep_w(
    const float* wq_w, const float* wk_w, const float* wv_w, const float* wo_w, const float* bo_w,
    const float* wq_h, const float* wk_h, const float* wv_h, const float* wo_h, const float* bo_h,
    const float* wq_t, const float* wk_t, const float* wv_t, const float* wo_t, const float* bo_t,
    u16* Wqkv, u16* WoCat, float* bo) {
  const int idx = blockIdx.x * 256 + threadIdx.x;
  if (idx < 2359296) {  // Wqkv row j = a*1536 + which*512 + co, col ci
    int j = idx >> 9, ci = idx & 511;
    int sel = j >> 9, co = j & 511;  // sel = a*3+which
    const float* s;
    switch (sel) {
      case 0: s = wq_w; break; case 1: s = wk_w; break; case 2: s = wv_w; break;
      case 3: s = wq_h; break; case 4: s = wk_h; break; case 5: s = wv_h; break;
      case 6: s = wq_t; break; case 7: s = wk_t; break; default: s = wv_t; break;
    }
    Wqkv[idx] = f2bf(s[co * 512 + ci]);
  } else if (idx < 2359296 + 786432) {  // WoCat[c][a*512+ci] = Wo_a[c][ci]
    int t = idx - 2359296;
    int c = t / 1536, j2 = t - c * 1536;
    int a = j2 >> 9, ci = j2 & 511;
    const float* s = (a == 0) ? wo_w : (a == 1) ? wo_h : wo_t;
    WoCat[t] = f2bf(s[c * 512 + ci]);
  } else if (idx < 2359296 + 786432 + 512) {
    int c = idx - (2359296 + 786432);
    bo[c] = bo_w[c] + bo_h[c] + bo_t[c];
  }
}

// ---------- GEMM: C(MxN) = A(MxK) * Bt(NxK)^T, bf16 out, 128x128 tile, BK=64 ----------
__global__ __launch_bounds__(256, 2) void k_gemm_bt(
    const u16* __restrict__ A, const u16* __restrict__ Bt, u16* __restrict__ Co,
    int K, int lda, int ldb, int ldc) {
  __shared__ __attribute__((aligned(16))) u16 lds[20480];  // 32KiB stage / 40KiB epilogue
  u16* ldsA = lds;
  u16* ldsB = lds + 8192;
  const int tid = threadIdx.x;
  const int lane = tid & 63, wave = tid >> 6;
  const int cl = lane & 15, q = lane >> 4;
  const int wm = (wave >> 1) * 64, wn = (wave & 1) * 64;
  const long m0 = (long)blockIdx.y * 128;
  const long n0 = (long)blockIdx.x * 128;
  const u16* Ab = A + m0 * lda;
  const u16* Bb = Bt + n0 * ldb;

  // staging: slot s holds global chunk (s&7)^(row&7) of row s>>3  (XOR swizzle)
  long a_off[4], b_off[4];
  u16 *a_dst[4], *b_dst[4];
#pragma unroll
  for (int i = 0; i < 4; i++) {
    int s = i * 256 + tid;
    int row = s >> 3;
    int gc = (s & 7) ^ (row & 7);
    a_off[i] = (long)row * lda + gc * 8;
    b_off[i] = (long)row * ldb + gc * 8;
    int slot0 = i * 256 + (tid & 192);  // wave-uniform LDS base
    a_dst[i] = ldsA + slot0 * 8;
    b_dst[i] = ldsB + slot0 * 8;
  }

  f4 acc[4][4];
  {
    f4 z; z[0] = z[1] = z[2] = z[3] = 0.f;
#pragma unroll
    for (int i = 0; i < 4; i++)
#pragma unroll
      for (int j = 0; j < 4; j++) acc[i][j] = z;
  }

  for (int kt = 0; kt < K; kt += 64) {
#pragma unroll
    for (int i = 0; i < 4; i++) {
      async_cp16(Ab + a_off[i] + kt, a_dst[i]);
      async_cp16(Bb + b_off[i] + kt, b_dst[i]);
    }
    __syncthreads();
#pragma unroll
    for (int kk = 0; kk < 2; kk++) {
      bf16x8 afr[4], bfr[4];
#pragma unroll
      for (int im = 0; im < 4; im++) {
        int row = wm + im * 16 + cl;
        int ch = (kk * 4 + q) ^ (row & 7);
        afr[im] = ld_frag(ldsA + row * 64 + ch * 8);
      }
#pragma unroll
      for (int in = 0; in < 4; in++) {
        int row = wn + in * 16 + cl;
        int ch = (kk * 4 + q) ^ (row & 7);
        bfr[in] = ld_frag(ldsB + row * 64 + ch * 8);
      }
#pragma unroll
      for (int im = 0; im < 4; im++)
#pragma unroll
        for (int in = 0; in < 4; in++)
          acc[im][in] = mfma_bf16(afr[im], bfr[in], acc[im][in]);
    }
    __syncthreads();
  }

  // bf16 epilogue: LDS repack -> coalesced 16B stores
  u16* myl = lds + wave * 5120;  // 64 rows x 80 (16B-aligned rows)
#pragma unroll
  for (int im = 0; im < 4; im++)
#pragma unroll
    for (int in = 0; in < 4; in++)
#pragma unroll
      for (int r = 0; r < 4; r++)
        myl[(im * 16 + q * 4 + r) * 80 + in * 16 + cl] = f2bf(acc[im][in][r]);
  __syncthreads();
#pragma unroll
  for (int it = 0; it < 8; it++) {
    int lr = it * 8 + (lane >> 3);
    int lc = (lane & 7) * 8;
    i4 v = *(const i4*)(myl + lr * 80 + lc);
    *(i4*)(Co + (m0 + wm + lr) * ldc + n0 + wn + lc) = v;
  }
}

// ---------- final GEMM: Out^T = WoCat(512x1536) @ oc(65536x1536)^T ----------
// 256x256 tile, 16 waves, BK=64, 64KB LDS; fp32 scatter to (B,C,THW) + bias.
// M-passes over oc reduced 4->2 vs generic kernel (oc is the HBM-bound stream).
__global__ __launch_bounds__(1024, 4) void k_gemm_final(
    const u16* __restrict__ A, const u16* __restrict__ Bt,
    float* __restrict__ Co, const float* __restrict__ bias) {
  __shared__ __attribute__((aligned(16))) u16 lds[32768];  // 64 KiB
  u16* ldsA = lds;
  u16* ldsB = lds + 16384;
  const int tid = threadIdx.x;
  const int lane = tid & 63, wave = tid >> 6;  // 16 waves
  const int cl = lane & 15, q = lane >> 4;
  const int wm = (wave >> 2) * 64, wn = (wave & 3) * 64;
  const int m0 = blockIdx.y * 256;
  const long n0 = (long)blockIdx.x * 256;
  const u16* Ab = A + (long)m0 * 1536;
  const u16* Bb = Bt + n0 * 1536;

  // staging: 2048 chunks each for A,B; 2 per thread; XOR swizzle as in k_gemm_bt
  long a_off[2];
  u16 *a_dst[2], *b_dst[2];
#pragma unroll
  for (int i = 0; i < 2; i++) {
    int s = i * 1024 + tid;
    int row = s >> 3;
    int gc = (s & 7) ^ (row & 7);
    a_off[i] = (long)row * 1536 + gc * 8;
    int slot0 = i * 1024 + (tid & 960);  // wave-uniform base (tid & ~63)
    a_dst[i] = ldsA + slot0 * 8;
    b_dst[i] = ldsB + slot0 * 8;
  }

  f4 acc[4][4];
  {
    f4 z; z[0] = z[1] = z[2] = z[3] = 0.f;
#pragma unroll
    for (int i = 0; i < 4; i++)
#pragma unroll
      for (int j = 0; j < 4; j++) acc[i][j] = z;
  }

  for (int kt = 0; kt < 1536; kt += 64) {
#pragma unroll
    for (int i = 0; i < 2; i++) {
      async_cp16(Ab + a_off[i] + kt, a_dst[i]);
      async_cp16(Bb + a_off[i] + kt, b_dst[i]);  // same geometry (ldb==lda==1536)
    }
    __syncthreads();
#pragma unroll
    for (int kk = 0; kk < 2; kk++) {
      bf16x8 afr[4], bfr[4];
#pragma unroll
      for (int im = 0; im < 4; im++) {
        int row = wm + im * 16 + cl;
        int ch = (kk * 4 + q) ^ (row & 7);
        afr[im] = ld_frag(ldsA + row * 64 + ch * 8);
      }
#pragma unroll
      for (int in = 0; in < 4; in++) {
        int row = wn + in * 16 + cl;
        int ch = (kk * 4 + q) ^ (row & 7);
        bfr[in] = ld_frag(ldsB + row * 64 + ch * 8);
      }
#pragma unroll
      for (int im = 0; im < 4; im++)
#pragma unroll
        for (int in = 0; in < 4; in++)
          acc[im][in] = mfma_bf16(afr[im], bfr[in], acc[im][in]);
    }
    __syncthreads();
  }

  // fp32 scatter epilogue: c-major rows, 16 lanes = 16 consecutive thw
#pragma unroll
  for (int im = 0; im < 4; im++)
#pragma unroll
    for (int r = 0; r < 4; r++) {
      int c = m0 + wm + im * 16 + q * 4 + r;
      float bv = bias[c];
#pragma unroll
      for (int in = 0; in < 4; in++) {
        long n = n0 + wn + in * 16 + cl;  // token
        long b = n >> 14, thw = n & 16383;
        Co[((b * 512 + c) << 14) + thw] = acc[im][in][r] + bv;
      }
    }
}

// ---------- axial attention: 1 wave per (group, head), MFMA QK^T and PV ----------
template <int L>
__global__ __launch_bounds__(64) void k_attn(
    const u16* __restrict__ QKV, u16* __restrict__ Oc,
    int inner, int istride, int ostride, int obase, int tstride) {
  constexpr int NT = L / 16;
  __shared__ __attribute__((aligned(16))) u16 sQ[2048];   // 32x64
  __shared__ __attribute__((aligned(16))) u16 sK[2048];   // 32x64
  __shared__ __attribute__((aligned(16))) u16 sVt[2560];  // 64ch x 40 (32 tok + pad)
  __shared__ __attribute__((aligned(16))) u16 sPbuf[(L == 16) ? 1280 : 1];
  u16* sP = (L == 16) ? sPbuf : sQ;  // L=32: sQ is dead after QK^T; alias saves LDS
  const int lane = threadIdx.x;
  const int cl = lane & 15, q = lane >> 4;
  const int g = blockIdx.x, head = blockIdx.y;
  const long tok0 = (long)(g / inner) * ostride + (long)(g % inner) * istride;
  const long rs = (long)tstride * 1536;
  const u16* qb = QKV + tok0 * 1536 + head * 64;
  const u16* kb = qb + 512;
  const u16* vb = qb + 1024;

  if (L == 16) {  // zero K-dim padding (cols 16..31 of P and Vt must be 0)
    unsigned int* z1 = (unsigned int*)sVt;
    for (int i = lane; i < 1280; i += 64) z1[i] = 0;
    unsigned int* z2 = (unsigned int*)sPbuf;
    for (int i = lane; i < 640; i += 64) z2[i] = 0;
  }

#pragma unroll
  for (int i = 0; i < L / 8; i++) {  // Q,K swizzled async stage
    int s = i * 64 + lane;
    int row = s >> 3;
    int gc = (s & 7) ^ (row & 7);
    async_cp16(qb + row * rs + gc * 8, (char*)sQ + i * 1024);
    async_cp16(kb + row * rs + gc * 8, (char*)sK + i * 1024);
  }
#pragma unroll
  for (int i = 0; i < L / 8; i++) {  // V load + transpose into sVt[ch][tok]
    int s = i * 64 + lane;
    int row = s >> 3, c8 = s & 7;
    union { i4 v; u16 h[8]; } raw;
    raw.v = *(const i4*)(vb + row * rs + c8 * 8);
#pragma unroll
    for (int j = 0; j < 8; j++) sVt[(c8 * 8 + j) * 40 + row] = raw.h[j];
  }
  __syncthreads();

  // S = Q K^T
  f4 sacc[NT][NT];
  { f4 z; z[0]=z[1]=z[2]=z[3]=0.f;
    for (int a = 0; a < NT; a++) for (int b2 = 0; b2 < NT; b2++) sacc[a][b2] = z; }
#pragma unroll
  for (int kk = 0; kk < 2; kk++) {
    bf16x8 qf[NT], kf[NT];
#pragma unroll
    for (int t = 0; t < NT; t++) {
      int row = t * 16 + cl;
      int ch = (kk * 4 + q) ^ (row & 7);
      qf[t] = ld_frag(sQ + row * 64 + ch * 8);
      kf[t] = ld_frag(sK + row * 64 + ch * 8);
    }
#pragma unroll
    for (int rt = 0; rt < NT; rt++)
#pragma unroll
      for (int ct = 0; ct < NT; ct++)
        sacc[rt][ct] = mfma_bf16(qf[rt], kf[ct], sacc[rt][ct]);
  }

  // softmax over keys; C-layout: row = q*4+i (+16*rt), col = cl (+16*ct)
#pragma unroll
  for (int rt = 0; rt < NT; rt++)
#pragma unroll
    for (int ct = 0; ct < NT; ct++)
#pragma unroll
      for (int i = 0; i < 4; i++) sacc[rt][ct][i] *= 0.125f;  // 1/sqrt(64)
#pragma unroll
  for (int rt = 0; rt < NT; rt++)
#pragma unroll
    for (int i = 0; i < 4; i++) {
      float m = sacc[rt][0][i];
#pragma unroll
      for (int ct = 1; ct < NT; ct++) m = fmaxf(m, sacc[rt][ct][i]);
      for (int off = 1; off < 16; off <<= 1) m = fmaxf(m, __shfl_xor(m, off, 64));
      float ssum = 0.f;
#pragma unroll
      for (int ct = 0; ct < NT; ct++) {
        float p = __expf(sacc[rt][ct][i] - m);
        sacc[rt][ct][i] = p;
        ssum += p;
      }
      for (int off = 1; off < 16; off <<= 1) ssum += __shfl_xor(ssum, off, 64);
      float inv = 1.0f / ssum;
#pragma unroll
      for (int ct = 0; ct < NT; ct++) sacc[rt][ct][i] *= inv;
    }

  // P -> LDS (A-operand layout source)
#pragma unroll
  for (int rt = 0; rt < NT; rt++)
#pragma unroll
    for (int ct = 0; ct < NT; ct++)
#pragma unroll
      for (int i = 0; i < 4; i++)
        sP[(rt * 16 + q * 4 + i) * 40 + ct * 16 + cl] = f2bf(sacc[rt][ct][i]);
  __syncthreads();

  // O = P V  (K=32, padded with zeros when L=16)
  bf16x8 pf[NT], vf[4];
#pragma unroll
  for (int mt = 0; mt < NT; mt++) pf[mt] = ld_frag(sP + (mt * 16 + cl) * 40 + q * 8);
#pragma unroll
  for (int nt = 0; nt < 4; nt++) vf[nt] = ld_frag(sVt + (nt * 16 + cl) * 40 + q * 8);
  f4 oacc[NT][4];
  { f4 z; z[0]=z[1]=z[2]=z[3]=0.f;
    for (int a = 0; a < NT; a++) for (int b2 = 0; b2 < 4; b2++) oacc[a][b2] = z; }
#pragma unroll
  for (int mt = 0; mt < NT; mt++)
#pragma unroll
    for (int nt = 0; nt < 4; nt++)
      oacc[mt][nt] = mfma_bf16(pf[mt], vf[nt], oacc[mt][nt]);

#pragma unroll
  for (int mt = 0; mt < NT; mt++)
#pragma unroll
    for (int i = 0; i < 4; i++) {
      int r = mt * 16 + q * 4 + i;  // token within group
      u16* dst = Oc + (tok0 + (long)r * tstride) * 1536 + obase + head * 64;
#pragma unroll
      for (int nt = 0; nt < 4; nt++) dst[nt * 16 + cl] = f2bf(oacc[mt][nt][i]);
    }
}

extern "C" void kernel_launch(void* const* d_in, const int* in_sizes, int n_in,
                              void* d_out, int out_size, void* d_ws, size_t ws_size,
                              hipStream_t stream) {
  (void)in_sizes; (void)n_in; (void)out_size; (void)ws_size;
  const float* x    = (const float*)d_in[0];
  const float* wq_w = (const float*)d_in[1];
  const float* wk_w = (const float*)d_in[2];
  const float* wv_w = (const float*)d_in[3];
  const float* wo_w = (const float*)d_in[4];
  const float* bo_w = (const float*)d_in[5];
  const float* wq_h = (const float*)d_in[6];
  const float* wk_h = (const float*)d_in[7];
  const float* wv_h = (const float*)d_in[8];
  const float* wo_h = (const float*)d_in[9];
  const float* bo_h = (const float*)d_in[10];
  const float* wq_t = (const float*)d_in[11];
  const float* wk_t = (const float*)d_in[12];
  const float* wv_t = (const float*)d_in[13];
  const float* wo_t = (const float*)d_in[14];
  const float* bo_t = (const float*)d_in[15];

  char* ws = (char*)d_ws;
  u16* xt    = (u16*)(ws);                 //  64 MiB  (65536 x 512 bf16)
  u16* qkv   = (u16*)(ws + 67108864L);     // 192 MiB  (65536 x 1536 bf16, per-branch)
  u16* oc    = (u16*)(ws + 268435456L);    // 192 MiB  (65536 x 1536 bf16 concat)
  u16* Wqkv  = (u16*)(ws + 469762048L);    // 4.5 MiB
  u16* WoCat = (u16*)(ws + 474480640L);    // 1.5 MiB
  float* bo  = (float*)(ws + 476053504L);  // 2 KiB

  k_transpose_x<<<dim3(512, 16, 4), 256, 0, stream>>>(x, xt);
  k_prep_w<<<dim3(12290), 256, 0, stream>>>(wq_w, wk_w, wv_w, wo_w, bo_w,
                                            wq_h, wk_h, wv_h, wo_h, bo_h,
                                            wq_t, wk_t, wv_t, wo_t, bo_t,
                                            Wqkv, WoCat, bo);
  for (int a = 0; a < 3; a++) {
    // QKV projection for branch a: (65536x512) @ (1536x512)^T -> (65536x1536) bf16
    k_gemm_bt<<<dim3(12, 512), 256, 0, stream>>>(
        xt, Wqkv + (long)a * 1536 * 512, qkv, 512, 512, 512, 1536);
    if (a == 0)        // width:  tok0 = g*32, stride 1
      k_attn<32><<<dim3(2048, 8), 64, 0, stream>>>(qkv, oc, 1, 0, 32, 0, 1);
    else if (a == 1)   // height: tok0 = (g/32)*1024 + g%32, stride 32
      k_attn<32><<<dim3(2048, 8), 64, 0, stream>>>(qkv, oc, 32, 1, 1024, 512, 32);
    else               // time:   tok0 = (g/1024)*16384 + g%1024, stride 1024, L=16
      k_attn<16><<<dim3(4096, 8), 64, 0, stream>>>(qkv, oc, 1024, 1, 16384, 1024, 1024);
  }
  // Out^T = WoCat(512x1536) @ oc(65536x1536)^T, +bias, scatter to (B,C,T,H,W) f32
  k_gemm_final<<<dim3(256, 2), 1024, 0, stream>>>(WoCat, oc, (float*)d_out, bo);
}